// Round 10
// baseline (345.455 us; speedup 1.0000x reference)
//
#include <hip/hip_runtime.h>
#include <hip/hip_bf16.h>
#include <stdint.h>

// ---------------------------------------------------------------------------
// EquivariantAttention on MI355X.  Dtype-adaptive (bf16 or fp32 inputs).
// R9: split-for-visibility showed all non-kB kernels < 53us but summing ~235us.
// R10: kB->4 quarters (cutoff ~27us names the hidden hog); kAgg rewritten
//   512-thr (jp x rr tasks, 8 waves/block, broadcast LDS reads); kQK z=4
//   (shorter VMEM chains); kA/kSM unsplit (reclaim dispatch overhead).
// ---------------------------------------------------------------------------

#define NNODES 512
#define NDIM   480

// ws layout (4-byte word offsets)
#define QS_OFF    0u         // 512*480 f32 q, per-head layout, folds applied
#define KT_OFF    245760u    // k packed: [h(8)][j4(15)][n(512)][4] f32
#define VB_OFF    491520u    // 512*480 f32 v, output-irrep (final) layout
#define ARE_OFF   737280u    // 512*288 u32 (bf16 pairs over o): [n][mi(9)][oc(32)]
#define ASN_OFF   884736u    // 512*288 u32
#define WF_OFF    1032192u   // 8192 f32: W1a[32][64]@0, W2T[64][64]@2048, W3[64][8]@6144, b1@6656, b2@6720, b3@6784
#define FLAG_OFF  1040384u   // flag[0] = 1 if inputs fp32, 0 if bf16
#define L_OFF     1040448u   // L SoA: [h(8)][r(512)][s(512)] f32 (8MB)
#define WTQ_OFF   3137600u   // q weights transposed [o][i] f32 + folds
#define WTK_OFF   3159104u
#define WTV_OFF   3180608u
#define W1T_OFF   3202112u   // mW1 transposed [o(64)][row(480)] f32, cg folded

__device__ __forceinline__ float bf2f(uint16_t u) {
    return __uint_as_float(((uint32_t)u) << 16);
}
__device__ __forceinline__ uint16_t f2bf(float f) {
    union { __hip_bfloat16 h; uint16_t u; } cv;
    cv.h = __float2bfloat16(f);
    return cv.u;
}
__device__ __forceinline__ float ldin(const void* p, size_t i, int f32) {
    return f32 ? ((const float*)p)[i] : bf2f(((const uint16_t*)p)[i]);
}
// tanh(x) = 1 - 2/(exp(2x)+1)
__device__ __forceinline__ float ftanh(float x) {
    float e = __builtin_amdgcn_exp2f(x * 2.885390081777927f);
    return 1.0f - 2.0f * __builtin_amdgcn_rcpf(e + 1.0f);
}

// ------------------------------------------------- dtype detector
__global__ __launch_bounds__(64) void kDet(const uint32_t* __restrict__ nf,
                                           int* __restrict__ flag)
{
    int t = threadIdx.x;
    uint32_t x = nf[64 + t];
    int e = (x >> 7) & 0xff;
    int good = (x != 0u) && (e >= 100) && (e <= 140);
    unsigned long long m = __ballot(good);
    if (t == 0) flag[0] = (__popcll(m) < 32) ? 1 : 0;
}

// ---------------------------------------------------------------- weights prep
#define NS 16384
__global__ __launch_bounds__(256) void kW(
    const void* __restrict__ mW1, const void* __restrict__ mb1,
    const void* __restrict__ mW2, const void* __restrict__ mb2,
    const void* __restrict__ mW3, const void* __restrict__ mb3,
    const void* __restrict__ Wq0, const void* __restrict__ Wq1, const void* __restrict__ Wq2,
    const void* __restrict__ Wk0, const void* __restrict__ Wk1, const void* __restrict__ Wk2,
    const void* __restrict__ Wv0, const void* __restrict__ Wv1, const void* __restrict__ Wv2,
    float* __restrict__ ws, const int* __restrict__ flagp)
{
    const int f32 = flagp[0];
    const int gt = blockIdx.x * 256 + threadIdx.x;
    float* Wf = ws + WF_OFF;

    for (int i = gt; i < 2048; i += NS) Wf[i] = ldin(mW1, i, f32);
    for (int i = gt; i < 4096; i += NS) {
        int o2 = i >> 6, ii = i & 63;
        Wf[2048 + i] = ldin(mW2, ii * 64 + o2, f32);
    }
    for (int i = gt; i < 512; i += NS) Wf[6144 + i] = ldin(mW3, i, f32);
    for (int i = gt; i < 64; i += NS) Wf[6656 + i] = ldin(mb1, i, f32);
    for (int i = gt; i < 64; i += NS) Wf[6720 + i] = ldin(mb2, i, f32);
    for (int i = gt; i < 8; i += NS)  Wf[6784 + i] = ldin(mb3, i, f32);

    const float e3n0 = 0.08838834764831845f, e3n1 = 0.125f, e3n2 = 0.17677669529663687f;
    const float cg1 = 0.5773502691896258f, cg2 = 0.4472135954999579f;
    const float attn = 0.1889822365046136f;

    const void* Wsrc[9] = {Wq0, Wq1, Wq2, Wk0, Wk1, Wk2, Wv0, Wv1, Wv2};
    float* Wdst[3] = {ws + WTQ_OFF, ws + WTK_OFF, ws + WTV_OFF};
    for (int kind = 0; kind < 3; ++kind) {
        const float f0 = (kind == 0) ? e3n0 * attn : e3n0;
        const float f1 = (kind == 0) ? e3n1 * cg1 * attn : e3n1;
        const float f2 = (kind == 0) ? e3n2 * cg2 * attn : e3n2;
        for (int i = gt; i < 16384; i += NS) {
            int o = i >> 7, ii = i & 127;
            Wdst[kind][i] = ldin(Wsrc[kind * 3], (size_t)ii * 128 + o, f32) * f0;
        }
        for (int i = gt; i < 4096; i += NS) {
            int o = i >> 6, ii = i & 63;
            Wdst[kind][16384 + i] = ldin(Wsrc[kind * 3 + 1], (size_t)ii * 64 + o, f32) * f1;
        }
        for (int i = gt; i < 1024; i += NS) {
            int o = i >> 5, ii = i & 31;
            Wdst[kind][20480 + i] = ldin(Wsrc[kind * 3 + 2], (size_t)ii * 32 + o, f32) * f2;
        }
    }
    float* W1T = ws + W1T_OFF;
    for (int i = gt; i < 30720; i += NS) {
        int o = i / 480, row = i - o * 480;
        float cgv;
        if (row < 160)      cgv = 1.0f;
        else if (row < 224) cgv = cg1;
        else if (row < 256) cgv = cg2;
        else if (row < 384) cgv = 1.0f;
        else if (row < 448) cgv = cg1;
        else                cgv = cg2;
        W1T[i] = ldin(mW1, (size_t)row * 64 + o, f32) * cgv;
    }
}

// ------------------------------------------------- per-node precompute
__global__ __launch_bounds__(256) void kA(
    const void* __restrict__ nfu,
    const float* __restrict__ WtQ, const float* __restrict__ WtK,
    const float* __restrict__ WtV, const float* __restrict__ W1T,
    float* __restrict__ qS, float* __restrict__ kT4, float* __restrict__ vB,
    uint32_t* __restrict__ ArecG, uint32_t* __restrict__ AsndG,
    const int* __restrict__ flagp)
{
    const int f32 = flagp[0];
    const int n = blockIdx.x, t = threadIdx.x;
    __shared__ float nfs[480];
    for (int i = t; i < 480; i += 256) nfs[i] = ldin(nfu, (size_t)n * 480 + i, f32);
    __syncthreads();

    for (int idx = t; idx < 1440; idx += 256) {
        int kind = idx / 480, rem = idx - kind * 480;
        int o, m, mul, d, off, am, qoff, sub;
        if (rem < 128)      { o = rem;           m = 0;          mul = 128; d = 1; off = 0;   am = 16; qoff = 0;  sub = 0; }
        else if (rem < 320) { int x = rem - 128; o = x / 3; m = x - o * 3; mul = 64;  d = 3; off = 128; am = 8;  qoff = 16; sub = 16384; }
        else                { int x = rem - 320; o = x / 5; m = x - o * 5; mul = 32;  d = 5; off = 320; am = 4;  qoff = 40; sub = 20480; }
        const float* base = (kind == 0) ? WtQ : (kind == 1) ? WtK : WtV;
        const float4* W4 = reinterpret_cast<const float4*>(base + sub + o * mul);
        const float* nf0 = nfs + off + m;
        float ax = 0.f, ay = 0.f, az = 0.f, aw = 0.f;
        const int n4 = mul >> 2;
        for (int i4 = 0; i4 < n4; ++i4) {
            float4 w = W4[i4];
            int ib = 4 * i4 * d;
            ax += nf0[ib]         * w.x;
            ay += nf0[ib + d]     * w.y;
            az += nf0[ib + 2 * d] * w.z;
            aw += nf0[ib + 3 * d] * w.w;
        }
        float acc = (ax + ay) + (az + aw);
        if (kind == 2) {
            vB[(size_t)n * 480 + rem] = acc;
        } else {
            int hh = o / am, a = o - hh * am;
            int j = qoff + a * d + m;
            if (kind == 0) qS[(size_t)n * 480 + hh * 60 + j] = acc;
            else           kT4[((size_t)(hh * 15 + (j >> 2)) * 512 + n) * 4 + (j & 3)] = acc;
        }
    }

    if (t < 128) {
        const int src = t >> 6, o = t & 63;
        float a[9];
        #pragma unroll
        for (int mi = 0; mi < 9; ++mi) {
            const int l = (mi == 0) ? 0 : (mi < 4 ? 1 : 2);
            const int m = (mi == 0) ? 0 : (mi < 4 ? mi - 1 : mi - 4);
            const int mul = (l == 0 ? 128 : l == 1 ? 64 : 32);
            const int d = 2 * l + 1;
            const int off = (l == 0 ? 0 : l == 1 ? 128 : 320);
            const int base = (src == 0) ? (l == 0 ? 32 : l == 1 ? 160 : 224)
                                        : (l == 0 ? 256 : l == 1 ? 384 : 448);
            const float4* W4 = reinterpret_cast<const float4*>(W1T + o * 480 + base);
            const float* nf0 = nfs + off + m;
            float ax = 0.f, ay = 0.f, az = 0.f, aw = 0.f;
            const int n4 = mul >> 2;
            for (int i4 = 0; i4 < n4; ++i4) {
                float4 w = W4[i4];
                int ib = 4 * i4 * d;
                ax += nf0[ib]         * w.x;
                ay += nf0[ib + d]     * w.y;
                az += nf0[ib + 2 * d] * w.z;
                aw += nf0[ib + 3 * d] * w.w;
            }
            a[mi] = (ax + ay) + (az + aw);
        }
        float b[9];
        #pragma unroll
        for (int mi = 0; mi < 9; ++mi) b[mi] = __shfl_xor(a[mi], 1, 64);
        if ((o & 1) == 0) {
            uint32_t* dst = (src ? AsndG : ArecG) + (size_t)n * 288 + (o >> 1);
            #pragma unroll
            for (int mi = 0; mi < 9; ++mi)
                dst[mi * 32] = ((uint32_t)f2bf(b[mi]) << 16) | (uint32_t)f2bf(a[mi]);
        }
    }
}

// ------------------------------------------------- q.k logits -> L (SoA)
// z splits heads into 4 pairs: 30-load chains, 1024 blocks.
__global__ __launch_bounds__(256) void kQK(
    const float* __restrict__ qS, const float* __restrict__ kT4,
    float* __restrict__ L)
{
    __shared__ float qL[16 * 120];        // [r16][(h-hb)*60 + j]
    const int t = threadIdx.x;
    const int lane = t & 63, wave = t >> 6;
    const int s0 = blockIdx.x * 64, r0 = blockIdx.y * 16, hb = blockIdx.z * 2;

    {
        float4* qL4 = reinterpret_cast<float4*>(qL);
        for (int i = t; i < 480; i += 256) {
            int rr = i / 30, c4 = i - rr * 30;
            qL4[i] = reinterpret_cast<const float4*>(
                         qS + (size_t)(r0 + rr) * 480 + hb * 60)[c4];
        }
    }
    __syncthreads();

    const int s = s0 + lane;
    const int rw = wave * 4;
    const float4* qL4 = reinterpret_cast<const float4*>(qL);
    const float4* k4  = reinterpret_cast<const float4*>(kT4);

    float acc[8];
    #pragma unroll
    for (int i = 0; i < 8; ++i) acc[i] = 0.f;

    #pragma unroll
    for (int h4 = 0; h4 < 2; ++h4) {
        const int h = hb + h4;
        #pragma unroll 5
        for (int j4 = 0; j4 < 15; ++j4) {
            float4 kv = k4[(size_t)(h * 15 + j4) * 512 + s];
            #pragma unroll
            for (int r = 0; r < 4; ++r) {
                float4 qv = qL4[(rw + r) * 30 + h4 * 15 + j4];
                acc[r * 2 + h4] += qv.x * kv.x + qv.y * kv.y + qv.z * kv.z + qv.w * kv.w;
            }
        }
    }
    #pragma unroll
    for (int r = 0; r < 4; ++r) {
        #pragma unroll
        for (int h4 = 0; h4 < 2; ++h4) {
            L[(((size_t)(hb + h4)) << 18) + (((size_t)(r0 + rw + r)) << 9) + s] = acc[r * 2 + h4];
        }
    }
}

// ------------------------------------------------- edge MLP (quarter-r grid)
__global__ __launch_bounds__(256) void kB(
    const void* __restrict__ eaG, const void* __restrict__ shG,
    const uint32_t* __restrict__ ArecG, const uint32_t* __restrict__ AsndG,
    const float* __restrict__ Wf, float* __restrict__ L,
    const int* __restrict__ flagp, int roff)
{
    __shared__ uint32_t ArecS[16 * 292];
    __shared__ uint32_t AsndS[16 * 292];
    const int f32 = flagp[0];
    const int t = threadIdx.x;
    const int s0 = blockIdx.x * 16, r0 = roff + blockIdx.y * 16;

    for (int i = t; i < 16 * 288; i += 256) {
        int row = i / 288, c = i - row * 288;
        ArecS[row * 292 + c] = ArecG[(size_t)(r0 + row) * 288 + c];
        AsndS[row * 292 + c] = AsndG[(size_t)(s0 + row) * 288 + c];
    }

    const int rl = t >> 4, sl = t & 15;
    const int r = r0 + rl, s = s0 + sl;
    const size_t eidx = (((size_t)r) << 9) + s;

    uint32_t eaR[16];
    if (f32) {
        const float4* ep = reinterpret_cast<const float4*>((const float*)eaG + eidx * 32);
        #pragma unroll
        for (int i = 0; i < 8; ++i) {
            float4 v = ep[i];
            eaR[2 * i]     = ((uint32_t)f2bf(v.y) << 16) | (uint32_t)f2bf(v.x);
            eaR[2 * i + 1] = ((uint32_t)f2bf(v.w) << 16) | (uint32_t)f2bf(v.z);
        }
    } else {
        const uint4* ep = reinterpret_cast<const uint4*>((const uint32_t*)eaG + eidx * 16);
        #pragma unroll
        for (int i = 0; i < 4; ++i) {
            uint4 v = ep[i];
            eaR[4 * i] = v.x; eaR[4 * i + 1] = v.y; eaR[4 * i + 2] = v.z; eaR[4 * i + 3] = v.w;
        }
    }

    float sh0, sh1, sh2, sh3, sh4, sh5, sh6, sh7, sh8;
    {
        const size_t sb = eidx * 9;
        if (f32) {
            const float* shp = (const float*)shG + sb;
            sh0 = shp[0]; sh1 = shp[1]; sh2 = shp[2]; sh3 = shp[3]; sh4 = shp[4];
            sh5 = shp[5]; sh6 = shp[6]; sh7 = shp[7]; sh8 = shp[8];
        } else {
            const uint16_t* shp = (const uint16_t*)shG + sb;
            sh0 = bf2f(shp[0]); sh1 = bf2f(shp[1]); sh2 = bf2f(shp[2]);
            sh3 = bf2f(shp[3]); sh4 = bf2f(shp[4]); sh5 = bf2f(shp[5]);
            sh6 = bf2f(shp[6]); sh7 = bf2f(shp[7]); sh8 = bf2f(shp[8]);
        }
    }

    float h[64];
    #pragma unroll
    for (int o = 0; o < 64; ++o) h[o] = Wf[6656 + o];   // b1

    __syncthreads();

    {
        const int rb = rl * 292, sb = sl * 292;
        #pragma unroll 1
        for (int mi = 0; mi < 9; ++mi) {
            float shv = sh0;
            shv = (mi == 1) ? sh1 : shv;  shv = (mi == 2) ? sh2 : shv;
            shv = (mi == 3) ? sh3 : shv;  shv = (mi == 4) ? sh4 : shv;
            shv = (mi == 5) ? sh5 : shv;  shv = (mi == 6) ? sh6 : shv;
            shv = (mi == 7) ? sh7 : shv;  shv = (mi == 8) ? sh8 : shv;
            const int ro = rb + mi * 32, so = sb + mi * 32;
            #pragma unroll
            for (int oc = 0; oc < 32; ++oc) {
                uint32_t pa = ArecS[ro + oc];
                uint32_t pb = AsndS[so + oc];
                float a0 = __uint_as_float(pa << 16);
                float b0 = __uint_as_float(pb << 16);
                float a1 = __uint_as_float(pa & 0xffff0000u);
                float b1 = __uint_as_float(pb & 0xffff0000u);
                h[2 * oc]     += shv * (a0 + b0);
                h[2 * oc + 1] += shv * (a1 + b1);
            }
        }
    }

    {
        #pragma unroll 1
        for (int cd = 0; cd < 16; ++cd) {
            uint32_t p = eaR[cd];
            float e0 = __uint_as_float(p << 16);
            float e1 = __uint_as_float(p & 0xffff0000u);
            const float* w0 = Wf + (2 * cd) * 64;
            #pragma unroll
            for (int o = 0; o < 64; ++o) h[o] += e0 * w0[o];
            #pragma unroll
            for (int o = 0; o < 64; ++o) h[o] += e1 * w0[64 + o];
        }
    }

    #pragma unroll
    for (int o = 0; o < 64; ++o) h[o] = ftanh(h[o]);

    float ew[8];
    #pragma unroll
    for (int hh = 0; hh < 8; ++hh) ew[hh] = Wf[6784 + hh];  // b3
    #pragma unroll 1
    for (int o2 = 0; o2 < 64; ++o2) {
        const float* w2 = Wf + 2048 + o2 * 64;
        float ac0 = Wf[6720 + o2], ac1 = 0.f;
        #pragma unroll
        for (int i = 0; i < 64; i += 2) {
            ac0 += h[i] * w2[i];
            ac1 += h[i + 1] * w2[i + 1];
        }
        float t2 = ftanh(ac0 + ac1);
        const float* w3 = Wf + 6144 + o2 * 8;
        #pragma unroll
        for (int hh = 0; hh < 8; ++hh) ew[hh] += t2 * w3[hh];
    }

    float* Lp = L + (((size_t)r) << 9) + s;
    #pragma unroll
    for (int hh = 0; hh < 8; ++hh) Lp[((size_t)hh) << 18] += ew[hh];
}

// ------------------------------------------------- softmax over senders (SoA)
__global__ __launch_bounds__(256) void kSM(float* __restrict__ L)
{
    const int r = blockIdx.x;
    const int w = threadIdx.x >> 6, lane = threadIdx.x & 63;
    const float C = 1.4426950408889634f;
    #pragma unroll
    for (int hi = 0; hi < 2; ++hi) {
        const int h = w * 2 + hi;
        float4* row4 = reinterpret_cast<float4*>(L + (((size_t)h) << 18) + (((size_t)r) << 9));
        float4 a = row4[lane * 2], b = row4[lane * 2 + 1];
        float m = fmaxf(fmaxf(fmaxf(a.x, a.y), fmaxf(a.z, a.w)),
                        fmaxf(fmaxf(b.x, b.y), fmaxf(b.z, b.w)));
        #pragma unroll
        for (int off = 32; off >= 1; off >>= 1) m = fmaxf(m, __shfl_xor(m, off, 64));
        a.x = __builtin_amdgcn_exp2f((a.x - m) * C);
        a.y = __builtin_amdgcn_exp2f((a.y - m) * C);
        a.z = __builtin_amdgcn_exp2f((a.z - m) * C);
        a.w = __builtin_amdgcn_exp2f((a.w - m) * C);
        b.x = __builtin_amdgcn_exp2f((b.x - m) * C);
        b.y = __builtin_amdgcn_exp2f((b.y - m) * C);
        b.z = __builtin_amdgcn_exp2f((b.z - m) * C);
        b.w = __builtin_amdgcn_exp2f((b.w - m) * C);
        float sm = (a.x + a.y) + (a.z + a.w) + (b.x + b.y) + (b.z + b.w);
        #pragma unroll
        for (int off = 32; off >= 1; off >>= 1) sm += __shfl_xor(sm, off, 64);
        float inv = __builtin_amdgcn_rcpf(sm);
        a.x *= inv; a.y *= inv; a.z *= inv; a.w *= inv;
        b.x *= inv; b.y *= inv; b.z *= inv; b.w *= inv;
        row4[lane * 2] = a; row4[lane * 2 + 1] = b;
    }
}

// ------------------------------------------------- aggregation + residual + store
// 512 threads: task = (j-pair, rr); 8 waves/block; LDS reads broadcast.
__global__ __launch_bounds__(512) void kAgg(
    const float* __restrict__ L, const float* __restrict__ vB,
    const void* __restrict__ nfu, void* __restrict__ out,
    const int* __restrict__ flagp)
{
    __shared__ float Ls[8192];             // [rr(2)][s(512)][h(8)]
    const int f32 = flagp[0];
    const int t = threadIdx.x;
    const int r0 = blockIdx.x * 2;

    for (int i = t; i < 8192; i += 512) {
        int rr = i >> 12, rem = i & 4095;
        int h = rem >> 9, s = rem & 511;
        Ls[rr * 4096 + s * 8 + h] =
            L[(((size_t)h) << 18) + (((size_t)(r0 + rr)) << 9) + s];
    }
    __syncthreads();

    if (t >= 480) return;
    const int jp = t >> 1, rr = t & 1;
    const int j0 = 2 * jp;
    int hh;
    if (j0 < 128)      hh = j0 >> 4;
    else if (j0 < 320) hh = (j0 - 128) / 24;
    else               hh = (j0 - 320) / 20;

    const float* Lrow = Ls + rr * 4096 + hh;
    float a0 = 0.f, a1 = 0.f;
    const float2* vp = reinterpret_cast<const float2*>(vB + j0);
    #pragma unroll 8
    for (int s = 0; s < 512; ++s) {
        float2 v = vp[(size_t)s * 240];
        float w = Lrow[s * 8];
        a0 += w * v.x; a1 += w * v.y;
    }

    const size_t o0 = (size_t)(r0 + rr) * 480 + j0;
    float r00 = ldin(nfu, o0, f32) + a0;
    float r01 = ldin(nfu, o0 + 1, f32) + a1;
    if (f32) {
        float* op = (float*)out;
        op[o0] = r00; op[o0 + 1] = r01;
    } else {
        uint16_t* op = (uint16_t*)out;
        op[o0] = f2bf(r00); op[o0 + 1] = f2bf(r01);
    }
}

extern "C" void kernel_launch(void* const* d_in, const int* in_sizes, int n_in,
                              void* d_out, int out_size, void* d_ws, size_t ws_size,
                              hipStream_t stream)
{
    (void)in_sizes; (void)n_in; (void)out_size; (void)ws_size;
    const void* nf  = d_in[0];
    const void* eaG = d_in[1];
    const void* shG = d_in[2];

    float* ws = (float*)d_ws;
    float* qS  = ws + QS_OFF;
    float* kT4 = ws + KT_OFF;
    float* vB  = ws + VB_OFF;
    uint32_t* ArecG = (uint32_t*)(ws + ARE_OFF);
    uint32_t* AsndG = (uint32_t*)(ws + ASN_OFF);
    float* Wf  = ws + WF_OFF;
    int* flag  = (int*)(ws + FLAG_OFF);
    float* L   = ws + L_OFF;
    float* WtQ = ws + WTQ_OFF;
    float* WtK = ws + WTK_OFF;
    float* WtV = ws + WTV_OFF;
    float* W1T = ws + W1T_OFF;

    kDet<<<1, 64, 0, stream>>>((const uint32_t*)nf, flag);
    kW<<<64, 256, 0, stream>>>(d_in[12], d_in[13], d_in[14], d_in[15], d_in[16], d_in[17],
                               d_in[3], d_in[4], d_in[5], d_in[6], d_in[7], d_in[8],
                               d_in[9], d_in[10], d_in[11], ws, flag);
    kA<<<512, 256, 0, stream>>>(nf, WtQ, WtK, WtV, W1T, qS, kT4, vB, ArecG, AsndG, flag);
    kQK<<<dim3(8, 32, 4), 256, 0, stream>>>(qS, kT4, L);
    kB<<<dim3(32, 8), 256, 0, stream>>>(eaG, shG, ArecG, AsndG, Wf, L, flag, 0);
    kB<<<dim3(32, 8), 256, 0, stream>>>(eaG, shG, ArecG, AsndG, Wf, L, flag, 128);
    kB<<<dim3(32, 8), 256, 0, stream>>>(eaG, shG, ArecG, AsndG, Wf, L, flag, 256);
    kB<<<dim3(32, 8), 256, 0, stream>>>(eaG, shG, ArecG, AsndG, Wf, L, flag, 384);
    kSM<<<512, 256, 0, stream>>>(L);
    kAgg<<<256, 512, 0, stream>>>(L, vB, nf, d_out, flag);
}

// Round 11
// 277.304 us; speedup vs baseline: 1.2458x; 1.2458x over previous
//
#include <hip/hip_runtime.h>
#include <hip/hip_bf16.h>
#include <stdint.h>

// ---------------------------------------------------------------------------
// EquivariantAttention on MI355X.  Dtype-adaptive (bf16 or fp32 inputs).
// R10 post-mortem: kB per-block critical path ~50us (scalar/LDS latency);
//   throughput needs co-resident partner blocks -> grid splits near-linearly
//   regress (full 97 / half 107 / quarter 200us).  Non-kB kernels all <50us.
// R11: consolidate — kB back to ONE full-grid dispatch; keep R10's kAgg
//   (512-thr broadcast), kQK z=4, single kA/kSM.
// ---------------------------------------------------------------------------

#define NNODES 512
#define NDIM   480

// ws layout (4-byte word offsets)
#define QS_OFF    0u         // 512*480 f32 q, per-head layout, folds applied
#define KT_OFF    245760u    // k packed: [h(8)][j4(15)][n(512)][4] f32
#define VB_OFF    491520u    // 512*480 f32 v, output-irrep (final) layout
#define ARE_OFF   737280u    // 512*288 u32 (bf16 pairs over o): [n][mi(9)][oc(32)]
#define ASN_OFF   884736u    // 512*288 u32
#define WF_OFF    1032192u   // 8192 f32: W1a[32][64]@0, W2T[64][64]@2048, W3[64][8]@6144, b1@6656, b2@6720, b3@6784
#define FLAG_OFF  1040384u   // flag[0] = 1 if inputs fp32, 0 if bf16
#define L_OFF     1040448u   // L SoA: [h(8)][r(512)][s(512)] f32 (8MB)
#define WTQ_OFF   3137600u   // q weights transposed [o][i] f32 + folds
#define WTK_OFF   3159104u
#define WTV_OFF   3180608u
#define W1T_OFF   3202112u   // mW1 transposed [o(64)][row(480)] f32, cg folded

__device__ __forceinline__ float bf2f(uint16_t u) {
    return __uint_as_float(((uint32_t)u) << 16);
}
__device__ __forceinline__ uint16_t f2bf(float f) {
    union { __hip_bfloat16 h; uint16_t u; } cv;
    cv.h = __float2bfloat16(f);
    return cv.u;
}
__device__ __forceinline__ float ldin(const void* p, size_t i, int f32) {
    return f32 ? ((const float*)p)[i] : bf2f(((const uint16_t*)p)[i]);
}
// tanh(x) = 1 - 2/(exp(2x)+1)
__device__ __forceinline__ float ftanh(float x) {
    float e = __builtin_amdgcn_exp2f(x * 2.885390081777927f);
    return 1.0f - 2.0f * __builtin_amdgcn_rcpf(e + 1.0f);
}

// ------------------------------------------------- dtype detector
__global__ __launch_bounds__(64) void kDet(const uint32_t* __restrict__ nf,
                                           int* __restrict__ flag)
{
    int t = threadIdx.x;
    uint32_t x = nf[64 + t];
    int e = (x >> 7) & 0xff;
    int good = (x != 0u) && (e >= 100) && (e <= 140);
    unsigned long long m = __ballot(good);
    if (t == 0) flag[0] = (__popcll(m) < 32) ? 1 : 0;
}

// ---------------------------------------------------------------- weights prep
#define NS 16384
__global__ __launch_bounds__(256) void kW(
    const void* __restrict__ mW1, const void* __restrict__ mb1,
    const void* __restrict__ mW2, const void* __restrict__ mb2,
    const void* __restrict__ mW3, const void* __restrict__ mb3,
    const void* __restrict__ Wq0, const void* __restrict__ Wq1, const void* __restrict__ Wq2,
    const void* __restrict__ Wk0, const void* __restrict__ Wk1, const void* __restrict__ Wk2,
    const void* __restrict__ Wv0, const void* __restrict__ Wv1, const void* __restrict__ Wv2,
    float* __restrict__ ws, const int* __restrict__ flagp)
{
    const int f32 = flagp[0];
    const int gt = blockIdx.x * 256 + threadIdx.x;
    float* Wf = ws + WF_OFF;

    for (int i = gt; i < 2048; i += NS) Wf[i] = ldin(mW1, i, f32);
    for (int i = gt; i < 4096; i += NS) {
        int o2 = i >> 6, ii = i & 63;
        Wf[2048 + i] = ldin(mW2, ii * 64 + o2, f32);
    }
    for (int i = gt; i < 512; i += NS) Wf[6144 + i] = ldin(mW3, i, f32);
    for (int i = gt; i < 64; i += NS) Wf[6656 + i] = ldin(mb1, i, f32);
    for (int i = gt; i < 64; i += NS) Wf[6720 + i] = ldin(mb2, i, f32);
    for (int i = gt; i < 8; i += NS)  Wf[6784 + i] = ldin(mb3, i, f32);

    const float e3n0 = 0.08838834764831845f, e3n1 = 0.125f, e3n2 = 0.17677669529663687f;
    const float cg1 = 0.5773502691896258f, cg2 = 0.4472135954999579f;
    const float attn = 0.1889822365046136f;

    const void* Wsrc[9] = {Wq0, Wq1, Wq2, Wk0, Wk1, Wk2, Wv0, Wv1, Wv2};
    float* Wdst[3] = {ws + WTQ_OFF, ws + WTK_OFF, ws + WTV_OFF};
    for (int kind = 0; kind < 3; ++kind) {
        const float f0 = (kind == 0) ? e3n0 * attn : e3n0;
        const float f1 = (kind == 0) ? e3n1 * cg1 * attn : e3n1;
        const float f2 = (kind == 0) ? e3n2 * cg2 * attn : e3n2;
        for (int i = gt; i < 16384; i += NS) {
            int o = i >> 7, ii = i & 127;
            Wdst[kind][i] = ldin(Wsrc[kind * 3], (size_t)ii * 128 + o, f32) * f0;
        }
        for (int i = gt; i < 4096; i += NS) {
            int o = i >> 6, ii = i & 63;
            Wdst[kind][16384 + i] = ldin(Wsrc[kind * 3 + 1], (size_t)ii * 64 + o, f32) * f1;
        }
        for (int i = gt; i < 1024; i += NS) {
            int o = i >> 5, ii = i & 31;
            Wdst[kind][20480 + i] = ldin(Wsrc[kind * 3 + 2], (size_t)ii * 32 + o, f32) * f2;
        }
    }
    float* W1T = ws + W1T_OFF;
    for (int i = gt; i < 30720; i += NS) {
        int o = i / 480, row = i - o * 480;
        float cgv;
        if (row < 160)      cgv = 1.0f;
        else if (row < 224) cgv = cg1;
        else if (row < 256) cgv = cg2;
        else if (row < 384) cgv = 1.0f;
        else if (row < 448) cgv = cg1;
        else                cgv = cg2;
        W1T[i] = ldin(mW1, (size_t)row * 64 + o, f32) * cgv;
    }
}

// ------------------------------------------------- per-node precompute
__global__ __launch_bounds__(256) void kA(
    const void* __restrict__ nfu,
    const float* __restrict__ WtQ, const float* __restrict__ WtK,
    const float* __restrict__ WtV, const float* __restrict__ W1T,
    float* __restrict__ qS, float* __restrict__ kT4, float* __restrict__ vB,
    uint32_t* __restrict__ ArecG, uint32_t* __restrict__ AsndG,
    const int* __restrict__ flagp)
{
    const int f32 = flagp[0];
    const int n = blockIdx.x, t = threadIdx.x;
    __shared__ float nfs[480];
    for (int i = t; i < 480; i += 256) nfs[i] = ldin(nfu, (size_t)n * 480 + i, f32);
    __syncthreads();

    for (int idx = t; idx < 1440; idx += 256) {
        int kind = idx / 480, rem = idx - kind * 480;
        int o, m, mul, d, off, am, qoff, sub;
        if (rem < 128)      { o = rem;           m = 0;          mul = 128; d = 1; off = 0;   am = 16; qoff = 0;  sub = 0; }
        else if (rem < 320) { int x = rem - 128; o = x / 3; m = x - o * 3; mul = 64;  d = 3; off = 128; am = 8;  qoff = 16; sub = 16384; }
        else                { int x = rem - 320; o = x / 5; m = x - o * 5; mul = 32;  d = 5; off = 320; am = 4;  qoff = 40; sub = 20480; }
        const float* base = (kind == 0) ? WtQ : (kind == 1) ? WtK : WtV;
        const float4* W4 = reinterpret_cast<const float4*>(base + sub + o * mul);
        const float* nf0 = nfs + off + m;
        float ax = 0.f, ay = 0.f, az = 0.f, aw = 0.f;
        const int n4 = mul >> 2;
        for (int i4 = 0; i4 < n4; ++i4) {
            float4 w = W4[i4];
            int ib = 4 * i4 * d;
            ax += nf0[ib]         * w.x;
            ay += nf0[ib + d]     * w.y;
            az += nf0[ib + 2 * d] * w.z;
            aw += nf0[ib + 3 * d] * w.w;
        }
        float acc = (ax + ay) + (az + aw);
        if (kind == 2) {
            vB[(size_t)n * 480 + rem] = acc;
        } else {
            int hh = o / am, a = o - hh * am;
            int j = qoff + a * d + m;
            if (kind == 0) qS[(size_t)n * 480 + hh * 60 + j] = acc;
            else           kT4[((size_t)(hh * 15 + (j >> 2)) * 512 + n) * 4 + (j & 3)] = acc;
        }
    }

    if (t < 128) {
        const int src = t >> 6, o = t & 63;
        float a[9];
        #pragma unroll
        for (int mi = 0; mi < 9; ++mi) {
            const int l = (mi == 0) ? 0 : (mi < 4 ? 1 : 2);
            const int m = (mi == 0) ? 0 : (mi < 4 ? mi - 1 : mi - 4);
            const int mul = (l == 0 ? 128 : l == 1 ? 64 : 32);
            const int d = 2 * l + 1;
            const int off = (l == 0 ? 0 : l == 1 ? 128 : 320);
            const int base = (src == 0) ? (l == 0 ? 32 : l == 1 ? 160 : 224)
                                        : (l == 0 ? 256 : l == 1 ? 384 : 448);
            const float4* W4 = reinterpret_cast<const float4*>(W1T + o * 480 + base);
            const float* nf0 = nfs + off + m;
            float ax = 0.f, ay = 0.f, az = 0.f, aw = 0.f;
            const int n4 = mul >> 2;
            for (int i4 = 0; i4 < n4; ++i4) {
                float4 w = W4[i4];
                int ib = 4 * i4 * d;
                ax += nf0[ib]         * w.x;
                ay += nf0[ib + d]     * w.y;
                az += nf0[ib + 2 * d] * w.z;
                aw += nf0[ib + 3 * d] * w.w;
            }
            a[mi] = (ax + ay) + (az + aw);
        }
        float b[9];
        #pragma unroll
        for (int mi = 0; mi < 9; ++mi) b[mi] = __shfl_xor(a[mi], 1, 64);
        if ((o & 1) == 0) {
            uint32_t* dst = (src ? AsndG : ArecG) + (size_t)n * 288 + (o >> 1);
            #pragma unroll
            for (int mi = 0; mi < 9; ++mi)
                dst[mi * 32] = ((uint32_t)f2bf(b[mi]) << 16) | (uint32_t)f2bf(a[mi]);
        }
    }
}

// ------------------------------------------------- q.k logits -> L (SoA)
__global__ __launch_bounds__(256) void kQK(
    const float* __restrict__ qS, const float* __restrict__ kT4,
    float* __restrict__ L)
{
    __shared__ float qL[16 * 120];        // [r16][(h-hb)*60 + j]
    const int t = threadIdx.x;
    const int lane = t & 63, wave = t >> 6;
    const int s0 = blockIdx.x * 64, r0 = blockIdx.y * 16, hb = blockIdx.z * 2;

    {
        float4* qL4 = reinterpret_cast<float4*>(qL);
        for (int i = t; i < 480; i += 256) {
            int rr = i / 30, c4 = i - rr * 30;
            qL4[i] = reinterpret_cast<const float4*>(
                         qS + (size_t)(r0 + rr) * 480 + hb * 60)[c4];
        }
    }
    __syncthreads();

    const int s = s0 + lane;
    const int rw = wave * 4;
    const float4* qL4 = reinterpret_cast<const float4*>(qL);
    const float4* k4  = reinterpret_cast<const float4*>(kT4);

    float acc[8];
    #pragma unroll
    for (int i = 0; i < 8; ++i) acc[i] = 0.f;

    #pragma unroll
    for (int h4 = 0; h4 < 2; ++h4) {
        const int h = hb + h4;
        #pragma unroll 5
        for (int j4 = 0; j4 < 15; ++j4) {
            float4 kv = k4[(size_t)(h * 15 + j4) * 512 + s];
            #pragma unroll
            for (int r = 0; r < 4; ++r) {
                float4 qv = qL4[(rw + r) * 30 + h4 * 15 + j4];
                acc[r * 2 + h4] += qv.x * kv.x + qv.y * kv.y + qv.z * kv.z + qv.w * kv.w;
            }
        }
    }
    #pragma unroll
    for (int r = 0; r < 4; ++r) {
        #pragma unroll
        for (int h4 = 0; h4 < 2; ++h4) {
            L[(((size_t)(hb + h4)) << 18) + (((size_t)(r0 + rw + r)) << 9) + s] = acc[r * 2 + h4];
        }
    }
}

// ------------------------------------------------- edge MLP (full grid)
__global__ __launch_bounds__(256) void kB(
    const void* __restrict__ eaG, const void* __restrict__ shG,
    const uint32_t* __restrict__ ArecG, const uint32_t* __restrict__ AsndG,
    const float* __restrict__ Wf, float* __restrict__ L,
    const int* __restrict__ flagp)
{
    __shared__ uint32_t ArecS[16 * 292];
    __shared__ uint32_t AsndS[16 * 292];
    const int f32 = flagp[0];
    const int t = threadIdx.x;
    const int s0 = blockIdx.x * 16, r0 = blockIdx.y * 16;

    for (int i = t; i < 16 * 288; i += 256) {
        int row = i / 288, c = i - row * 288;
        ArecS[row * 292 + c] = ArecG[(size_t)(r0 + row) * 288 + c];
        AsndS[row * 292 + c] = AsndG[(size_t)(s0 + row) * 288 + c];
    }

    const int rl = t >> 4, sl = t & 15;
    const int r = r0 + rl, s = s0 + sl;
    const size_t eidx = (((size_t)r) << 9) + s;

    uint32_t eaR[16];
    if (f32) {
        const float4* ep = reinterpret_cast<const float4*>((const float*)eaG + eidx * 32);
        #pragma unroll
        for (int i = 0; i < 8; ++i) {
            float4 v = ep[i];
            eaR[2 * i]     = ((uint32_t)f2bf(v.y) << 16) | (uint32_t)f2bf(v.x);
            eaR[2 * i + 1] = ((uint32_t)f2bf(v.w) << 16) | (uint32_t)f2bf(v.z);
        }
    } else {
        const uint4* ep = reinterpret_cast<const uint4*>((const uint32_t*)eaG + eidx * 16);
        #pragma unroll
        for (int i = 0; i < 4; ++i) {
            uint4 v = ep[i];
            eaR[4 * i] = v.x; eaR[4 * i + 1] = v.y; eaR[4 * i + 2] = v.z; eaR[4 * i + 3] = v.w;
        }
    }

    float sh0, sh1, sh2, sh3, sh4, sh5, sh6, sh7, sh8;
    {
        const size_t sb = eidx * 9;
        if (f32) {
            const float* shp = (const float*)shG + sb;
            sh0 = shp[0]; sh1 = shp[1]; sh2 = shp[2]; sh3 = shp[3]; sh4 = shp[4];
            sh5 = shp[5]; sh6 = shp[6]; sh7 = shp[7]; sh8 = shp[8];
        } else {
            const uint16_t* shp = (const uint16_t*)shG + sb;
            sh0 = bf2f(shp[0]); sh1 = bf2f(shp[1]); sh2 = bf2f(shp[2]);
            sh3 = bf2f(shp[3]); sh4 = bf2f(shp[4]); sh5 = bf2f(shp[5]);
            sh6 = bf2f(shp[6]); sh7 = bf2f(shp[7]); sh8 = bf2f(shp[8]);
        }
    }

    float h[64];
    #pragma unroll
    for (int o = 0; o < 64; ++o) h[o] = Wf[6656 + o];   // b1

    __syncthreads();

    {
        const int rb = rl * 292, sb = sl * 292;
        #pragma unroll 1
        for (int mi = 0; mi < 9; ++mi) {
            float shv = sh0;
            shv = (mi == 1) ? sh1 : shv;  shv = (mi == 2) ? sh2 : shv;
            shv = (mi == 3) ? sh3 : shv;  shv = (mi == 4) ? sh4 : shv;
            shv = (mi == 5) ? sh5 : shv;  shv = (mi == 6) ? sh6 : shv;
            shv = (mi == 7) ? sh7 : shv;  shv = (mi == 8) ? sh8 : shv;
            const int ro = rb + mi * 32, so = sb + mi * 32;
            #pragma unroll
            for (int oc = 0; oc < 32; ++oc) {
                uint32_t pa = ArecS[ro + oc];
                uint32_t pb = AsndS[so + oc];
                float a0 = __uint_as_float(pa << 16);
                float b0 = __uint_as_float(pb << 16);
                float a1 = __uint_as_float(pa & 0xffff0000u);
                float b1 = __uint_as_float(pb & 0xffff0000u);
                h[2 * oc]     += shv * (a0 + b0);
                h[2 * oc + 1] += shv * (a1 + b1);
            }
        }
    }

    {
        #pragma unroll 1
        for (int cd = 0; cd < 16; ++cd) {
            uint32_t p = eaR[cd];
            float e0 = __uint_as_float(p << 16);
            float e1 = __uint_as_float(p & 0xffff0000u);
            const float* w0 = Wf + (2 * cd) * 64;
            #pragma unroll
            for (int o = 0; o < 64; ++o) h[o] += e0 * w0[o];
            #pragma unroll
            for (int o = 0; o < 64; ++o) h[o] += e1 * w0[64 + o];
        }
    }

    #pragma unroll
    for (int o = 0; o < 64; ++o) h[o] = ftanh(h[o]);

    float ew[8];
    #pragma unroll
    for (int hh = 0; hh < 8; ++hh) ew[hh] = Wf[6784 + hh];  // b3
    #pragma unroll 1
    for (int o2 = 0; o2 < 64; ++o2) {
        const float* w2 = Wf + 2048 + o2 * 64;
        float ac0 = Wf[6720 + o2], ac1 = 0.f;
        #pragma unroll
        for (int i = 0; i < 64; i += 2) {
            ac0 += h[i] * w2[i];
            ac1 += h[i + 1] * w2[i + 1];
        }
        float t2 = ftanh(ac0 + ac1);
        const float* w3 = Wf + 6144 + o2 * 8;
        #pragma unroll
        for (int hh = 0; hh < 8; ++hh) ew[hh] += t2 * w3[hh];
    }

    float* Lp = L + (((size_t)r) << 9) + s;
    #pragma unroll
    for (int hh = 0; hh < 8; ++hh) Lp[((size_t)hh) << 18] += ew[hh];
}

// ------------------------------------------------- softmax over senders (SoA)
__global__ __launch_bounds__(256) void kSM(float* __restrict__ L)
{
    const int r = blockIdx.x;
    const int w = threadIdx.x >> 6, lane = threadIdx.x & 63;
    const float C = 1.4426950408889634f;
    #pragma unroll
    for (int hi = 0; hi < 2; ++hi) {
        const int h = w * 2 + hi;
        float4* row4 = reinterpret_cast<float4*>(L + (((size_t)h) << 18) + (((size_t)r) << 9));
        float4 a = row4[lane * 2], b = row4[lane * 2 + 1];
        float m = fmaxf(fmaxf(fmaxf(a.x, a.y), fmaxf(a.z, a.w)),
                        fmaxf(fmaxf(b.x, b.y), fmaxf(b.z, b.w)));
        #pragma unroll
        for (int off = 32; off >= 1; off >>= 1) m = fmaxf(m, __shfl_xor(m, off, 64));
        a.x = __builtin_amdgcn_exp2f((a.x - m) * C);
        a.y = __builtin_amdgcn_exp2f((a.y - m) * C);
        a.z = __builtin_amdgcn_exp2f((a.z - m) * C);
        a.w = __builtin_amdgcn_exp2f((a.w - m) * C);
        b.x = __builtin_amdgcn_exp2f((b.x - m) * C);
        b.y = __builtin_amdgcn_exp2f((b.y - m) * C);
        b.z = __builtin_amdgcn_exp2f((b.z - m) * C);
        b.w = __builtin_amdgcn_exp2f((b.w - m) * C);
        float sm = (a.x + a.y) + (a.z + a.w) + (b.x + b.y) + (b.z + b.w);
        #pragma unroll
        for (int off = 32; off >= 1; off >>= 1) sm += __shfl_xor(sm, off, 64);
        float inv = __builtin_amdgcn_rcpf(sm);
        a.x *= inv; a.y *= inv; a.z *= inv; a.w *= inv;
        b.x *= inv; b.y *= inv; b.z *= inv; b.w *= inv;
        row4[lane * 2] = a; row4[lane * 2 + 1] = b;
    }
}

// ------------------------------------------------- aggregation + residual + store
// 512 threads: task = (j-pair, rr); 8 waves/block; LDS reads broadcast.
__global__ __launch_bounds__(512) void kAgg(
    const float* __restrict__ L, const float* __restrict__ vB,
    const void* __restrict__ nfu, void* __restrict__ out,
    const int* __restrict__ flagp)
{
    __shared__ float Ls[8192];             // [rr(2)][s(512)][h(8)]
    const int f32 = flagp[0];
    const int t = threadIdx.x;
    const int r0 = blockIdx.x * 2;

    for (int i = t; i < 8192; i += 512) {
        int rr = i >> 12, rem = i & 4095;
        int h = rem >> 9, s = rem & 511;
        Ls[rr * 4096 + s * 8 + h] =
            L[(((size_t)h) << 18) + (((size_t)(r0 + rr)) << 9) + s];
    }
    __syncthreads();

    if (t >= 480) return;
    const int jp = t >> 1, rr = t & 1;
    const int j0 = 2 * jp;
    int hh;
    if (j0 < 128)      hh = j0 >> 4;
    else if (j0 < 320) hh = (j0 - 128) / 24;
    else               hh = (j0 - 320) / 20;

    const float* Lrow = Ls + rr * 4096 + hh;
    float a0 = 0.f, a1 = 0.f;
    const float2* vp = reinterpret_cast<const float2*>(vB + j0);
    #pragma unroll 8
    for (int s = 0; s < 512; ++s) {
        float2 v = vp[(size_t)s * 240];
        float w = Lrow[s * 8];
        a0 += w * v.x; a1 += w * v.y;
    }

    const size_t o0 = (size_t)(r0 + rr) * 480 + j0;
    float r00 = ldin(nfu, o0, f32) + a0;
    float r01 = ldin(nfu, o0 + 1, f32) + a1;
    if (f32) {
        float* op = (float*)out;
        op[o0] = r00; op[o0 + 1] = r01;
    } else {
        uint16_t* op = (uint16_t*)out;
        op[o0] = f2bf(r00); op[o0 + 1] = f2bf(r01);
    }
}

extern "C" void kernel_launch(void* const* d_in, const int* in_sizes, int n_in,
                              void* d_out, int out_size, void* d_ws, size_t ws_size,
                              hipStream_t stream)
{
    (void)in_sizes; (void)n_in; (void)out_size; (void)ws_size;
    const void* nf  = d_in[0];
    const void* eaG = d_in[1];
    const void* shG = d_in[2];

    float* ws = (float*)d_ws;
    float* qS  = ws + QS_OFF;
    float* kT4 = ws + KT_OFF;
    float* vB  = ws + VB_OFF;
    uint32_t* ArecG = (uint32_t*)(ws + ARE_OFF);
    uint32_t* AsndG = (uint32_t*)(ws + ASN_OFF);
    float* Wf  = ws + WF_OFF;
    int* flag  = (int*)(ws + FLAG_OFF);
    float* L   = ws + L_OFF;
    float* WtQ = ws + WTQ_OFF;
    float* WtK = ws + WTK_OFF;
    float* WtV = ws + WTV_OFF;
    float* W1T = ws + W1T_OFF;

    kDet<<<1, 64, 0, stream>>>((const uint32_t*)nf, flag);
    kW<<<64, 256, 0, stream>>>(d_in[12], d_in[13], d_in[14], d_in[15], d_in[16], d_in[17],
                               d_in[3], d_in[4], d_in[5], d_in[6], d_in[7], d_in[8],
                               d_in[9], d_in[10], d_in[11], ws, flag);
    kA<<<512, 256, 0, stream>>>(nf, WtQ, WtK, WtV, W1T, qS, kT4, vB, ArecG, AsndG, flag);
    kQK<<<dim3(8, 32, 4), 256, 0, stream>>>(qS, kT4, L);
    kB<<<dim3(32, 32), 256, 0, stream>>>(eaG, shG, ArecG, AsndG, Wf, L, flag);
    kSM<<<512, 256, 0, stream>>>(L);
    kAgg<<<256, 512, 0, stream>>>(L, vB, nf, d_out, flag);
}